// Round 2
// baseline (434.878 us; speedup 1.0000x reference)
//
#include <hip/hip_runtime.h>
#include <hip/hip_bf16.h>

#define CIN 128
#define COUT 128
#define HH 112
#define WW 112
#define HW (HH*WW)      // 12544
#define K3 384          // 3*CIN
#define NB_ALL 16

typedef float f32x4 __attribute__((ext_vector_type(4)));
typedef short bf16x8 __attribute__((ext_vector_type(8)));

// ---------------- kernel 0: abc (384x128 f32) -> abc_t (128x384 bf16) ----------------
__global__ __launch_bounds__(256) void k_abct(const float* __restrict__ abc,
                                              __hip_bfloat16* __restrict__ abct) {
    int idx = blockIdx.x * 256 + threadIdx.x;
    if (idx >= K3 * COUT) return;
    int o = idx & 127, k = idx >> 7;
    abct[o * K3 + k] = __float2bfloat16(abc[k * COUT + o]);
}

// ---------------- kernel 1: separable box sums -> dcg k8-packed bf16 ----------------
// dcg layout: [kb=k/8][m][e=k%8], m = bb*HW + i*WW + j  (bb = batch within chunk)
// k = part*128 + c, part 0=xpart(Sx) 1=ypart(Sy) 2=const(S)
// block: 128 threads: c_off = t&7, j_off = t>>3 (0..15)
// grid.x = nb * 16(cg) * 7(jg) * 2(ig)
__global__ __launch_bounds__(128) void k_boxsum(const float* __restrict__ x,
                                                __hip_bfloat16* __restrict__ dcg,
                                                int chunk_base, int Mc) {
    int bidx = blockIdx.x;
    int ig = bidx & 1; bidx >>= 1;
    int jg = bidx % 7; bidx /= 7;
    int cg = bidx & 15;
    int bb = bidx >> 4;
    int t = threadIdx.x;
    int c = cg * 8 + (t & 7);
    int j = jg * 16 + (t >> 3);

    const float* xc = x + ((size_t)(chunk_base + bb) * CIN + c) * HW;

    int i0 = ig * 56, i1 = i0 + 56;

    float hp[7], hy[7];

    // compute one horizontal pair for row r (zero if row outside image)
#define HPAIR(r, HP, HY) do {                                                  \
    int _r = (r);                                                              \
    if (_r < 0 || _r >= HH) { HP = 0.f; HY = 0.f; }                            \
    else {                                                                     \
        const float* row = xc + _r * WW;                                       \
        float s0 = (j-3 >= 0) ? row[j-3] : 0.f;                                \
        float s1 = (j-2 >= 0) ? row[j-2] : 0.f;                                \
        float s2 = (j-1 >= 0) ? row[j-1] : 0.f;                                \
        float s3 = row[j];                                                     \
        float s4 = (j+1 < WW) ? row[j+1] : 0.f;                                \
        float s5 = (j+2 < WW) ? row[j+2] : 0.f;                                \
        float s6 = (j+3 < WW) ? row[j+3] : 0.f;                                \
        HP = ((s0+s6)+(s1+s5)) + ((s2+s4)+s3);                                 \
        HY = 3.f*(s6-s0) + 2.f*(s5-s1) + (s4-s2);                              \
    }                                                                          \
} while (0)

#pragma unroll
    for (int q = 0; q < 6; ++q) { HPAIR(i0 - 3 + q, hp[q], hy[q]); }

    int cb = c >> 3, e = c & 7;
    __hip_bfloat16* d0 = dcg + (size_t)(0 * 16 + cb) * (size_t)Mc * 8 + e;
    __hip_bfloat16* d1 = dcg + (size_t)(1 * 16 + cb) * (size_t)Mc * 8 + e;
    __hip_bfloat16* d2 = dcg + (size_t)(2 * 16 + cb) * (size_t)Mc * 8 + e;
    size_t mb = (size_t)bb * HW + (size_t)i0 * WW + j;

    for (int i = i0; i < i1; ++i) {
        HPAIR(i + 3, hp[6], hy[6]);
        float S  = ((hp[0]+hp[6])+(hp[1]+hp[5])) + ((hp[2]+hp[4])+hp[3]);
        float Sx = 3.f*(hp[6]-hp[0]) + 2.f*(hp[5]-hp[1]) + (hp[4]-hp[2]);
        float Sy = ((hy[0]+hy[6])+(hy[1]+hy[5])) + ((hy[2]+hy[4])+hy[3]);
        size_t m8 = mb * 8;
        d0[m8] = __float2bfloat16(Sx);
        d1[m8] = __float2bfloat16(Sy);
        d2[m8] = __float2bfloat16(S);
        mb += WW;
#pragma unroll
        for (int q = 0; q < 6; ++q) { hp[q] = hp[q+1]; hy[q] = hy[q+1]; }
    }
#undef HPAIR
}

// ---------------- kernel 2: GEMM out[m][o] = sum_k dcg[k][m]*abc[k][o] + bias ----------------
// block = 256 thr = 4 waves; wave w handles o in [w*32, w*32+32), pixel tile of 32.
// A-operand (MFMA M dim) = abc_t rows (o), B-operand (N dim) = pixels.
// grid.x = nb * 392   (12544/32 = 392 pixel tiles per batch)
__global__ __launch_bounds__(256, 2) void k_gemm(const __hip_bfloat16* __restrict__ dcg,
                                                 const __hip_bfloat16* __restrict__ abct,
                                                 const float* __restrict__ bias,
                                                 float* __restrict__ out,
                                                 int chunk_base, int Mc) {
    int tile = blockIdx.x;
    int bb = tile / 392;
    int mt = tile % 392;
    int m0 = mt * 32;

    int l  = threadIdx.x & 63;
    int w  = threadIdx.x >> 6;
    int o0 = w * 32;
    int lg = l >> 4;      // k-group within fragment
    int lr = l & 15;      // row/col within fragment

    const ushort* at = (const ushort*)abct;
    const ushort* dg = (const ushort*)dcg;

    // preload all abc A-fragments for this wave's 32 output channels (96 VGPRs)
    bf16x8 afrag[12][2];
#pragma unroll
    for (int kc = 0; kc < 12; ++kc)
#pragma unroll
        for (int fi = 0; fi < 2; ++fi) {
            const ushort* p = at + (size_t)(o0 + fi * 16 + lr) * K3 + kc * 32 + lg * 8;
            afrag[kc][fi] = *(const bf16x8*)p;
        }

    f32x4 acc[2][2] = {};
    size_t mbase = (size_t)bb * HW + m0;

#pragma unroll
    for (int kc = 0; kc < 12; ++kc) {
        bf16x8 bfrag[2];
#pragma unroll
        for (int pj = 0; pj < 2; ++pj) {
            const ushort* p = dg + ((size_t)(kc * 4 + lg) * Mc + mbase + pj * 16 + lr) * 8;
            bfrag[pj] = *(const bf16x8*)p;
        }
#pragma unroll
        for (int fi = 0; fi < 2; ++fi)
#pragma unroll
            for (int pj = 0; pj < 2; ++pj)
                acc[fi][pj] = __builtin_amdgcn_mfma_f32_16x16x32_bf16(
                    afrag[kc][fi], bfrag[pj], acc[fi][pj], 0, 0, 0);
    }

    // store: D col = pixel (lr), row = o = o0 + fi*16 + lg*4 + r
    int b = chunk_base + bb;
#pragma unroll
    for (int fi = 0; fi < 2; ++fi) {
#pragma unroll
        for (int r = 0; r < 4; ++r) {
            int o = o0 + fi * 16 + lg * 4 + r;
            float bv = bias[o];
            float* po = out + ((size_t)b * COUT + o) * HW + m0 + lr;
#pragma unroll
            for (int pj = 0; pj < 2; ++pj)
                po[pj * 16] = acc[fi][pj][r] + bv;
        }
    }
}

// ---------------- launcher ----------------
extern "C" void kernel_launch(void* const* d_in, const int* in_sizes, int n_in,
                              void* d_out, int out_size, void* d_ws, size_t ws_size,
                              hipStream_t stream) {
    const float* x    = (const float*)d_in[0];
    const float* abc  = (const float*)d_in[1];
    const float* bias = (const float*)d_in[2];
    float* out = (float*)d_out;

    char* ws = (char*)d_ws;
    __hip_bfloat16* abct = (__hip_bfloat16*)ws;                  // 96 KB
    __hip_bfloat16* dcg  = (__hip_bfloat16*)(ws + 131072);       // 16B-aligned

    const size_t per_batch = (size_t)48 * HW * 16;               // 9,633,792 B
    size_t avail = (ws_size > 131072) ? ws_size - 131072 : 0;
    int nb = (int)(avail / per_batch);
    if (nb > NB_ALL) nb = NB_ALL;
    if (nb < 1) nb = 1;   // assume workspace is at least ~10 MB

    k_abct<<<dim3((K3 * COUT + 255) / 256), dim3(256), 0, stream>>>(abc, abct);

    for (int b0 = 0; b0 < NB_ALL; b0 += nb) {
        int nbc = (NB_ALL - b0 < nb) ? (NB_ALL - b0) : nb;
        int Mc = nbc * HW;
        k_boxsum<<<dim3(nbc * 16 * 7 * 2), dim3(128), 0, stream>>>(x, dcg, b0, Mc);
        k_gemm<<<dim3(nbc * 392), dim3(256), 0, stream>>>(dcg, abct, bias, out, b0, Mc);
    }
}

// Round 4
// 379.262 us; speedup vs baseline: 1.1466x; 1.1466x over previous
//
#include <hip/hip_runtime.h>
#include <hip/hip_bf16.h>

#define CIN 128
#define COUT 128
#define HH 112
#define WW 112
#define HW (HH*WW)      // 12544
#define K3 384          // 3*CIN
#define NB_ALL 16

typedef float f32x4 __attribute__((ext_vector_type(4)));
typedef short bf16x8 __attribute__((ext_vector_type(8)));

// ---------------- kernel 0: abc (384x128 f32) -> abc_t (128x384 bf16) ----------------
__global__ __launch_bounds__(256) void k_abct(const float* __restrict__ abc,
                                              __hip_bfloat16* __restrict__ abct) {
    int idx = blockIdx.x * 256 + threadIdx.x;
    if (idx >= K3 * COUT) return;
    int o = idx & 127, k = idx >> 7;
    abct[o * K3 + k] = __float2bfloat16(abc[k * COUT + o]);
}

// ---------------- kernel 1: separable box sums -> dcg k8-packed bf16 ----------------
// dcg layout: [kb=k/8][m][e=k%8], m = bb*HW + i*WW + j
// k = part*128 + c, part 0=xpart(Sx) 1=ypart(Sy) 2=const(S)
// block: 512 threads = 8 waves; wave w -> channel c = cg*8+w (so e=w, kb part*16+cg)
// each wave covers a full 112-wide row as two 56-lane halves (lanes j-contiguous)
// grid.x = nbc * 16(cg) * 4(ig row strips of 28)
__global__ __launch_bounds__(512) void k_boxsum(const float* __restrict__ x,
                                                __hip_bfloat16* __restrict__ dcg,
                                                int chunk_base, int Mc) {
    int bidx = blockIdx.x;
    int ig = bidx & 3; bidx >>= 2;
    int cg = bidx & 15; bidx >>= 4;
    int bb = bidx;
    int w    = threadIdx.x >> 6;
    int lane = threadIdx.x & 63;
    int c = cg * 8 + w;

    const float* xc = x + ((size_t)(chunk_base + bb) * CIN + c) * HW;

    int i0 = ig * 28;
    bool act = lane < 56;
    int j0 = lane;        // half 0 output col
    int j1 = 56 + lane;   // half 1 output col

    float hp0[7], hy0[7], hp1[7], hy1[7];

    // horizontal pair for row r at output col j (fully guarded loads)
#define HPAIR(r, j, HP, HY) do {                                               \
    int _r = (r);                                                              \
    if ((unsigned)_r >= HH) { HP = 0.f; HY = 0.f; }                            \
    else {                                                                     \
        const float* row = xc + _r * WW;                                       \
        int _j = (j);                                                          \
        float s0 = ((unsigned)(_j-3) < WW) ? row[_j-3] : 0.f;                  \
        float s1 = ((unsigned)(_j-2) < WW) ? row[_j-2] : 0.f;                  \
        float s2 = ((unsigned)(_j-1) < WW) ? row[_j-1] : 0.f;                  \
        float s3 = ((unsigned)(_j  ) < WW) ? row[_j  ] : 0.f;                  \
        float s4 = ((unsigned)(_j+1) < WW) ? row[_j+1] : 0.f;                  \
        float s5 = ((unsigned)(_j+2) < WW) ? row[_j+2] : 0.f;                  \
        float s6 = ((unsigned)(_j+3) < WW) ? row[_j+3] : 0.f;                  \
        HP = ((s0+s6)+(s1+s5)) + ((s2+s4)+s3);                                 \
        HY = 3.f*(s6-s0) + 2.f*(s5-s1) + (s4-s2);                              \
    }                                                                          \
} while (0)

#pragma unroll
    for (int q = 0; q < 6; ++q) {
        HPAIR(i0 - 3 + q, j0, hp0[q], hy0[q]);
        HPAIR(i0 - 3 + q, j1, hp1[q], hy1[q]);
    }

    __hip_bfloat16* d0 = dcg + (size_t)(0 * 16 + cg) * (size_t)Mc * 8 + w;
    __hip_bfloat16* d1 = dcg + (size_t)(1 * 16 + cg) * (size_t)Mc * 8 + w;
    __hip_bfloat16* d2 = dcg + (size_t)(2 * 16 + cg) * (size_t)Mc * 8 + w;

    size_t mrow = (size_t)bb * HW + (size_t)i0 * WW;

    for (int i = i0; i < i0 + 28; ++i) {
        HPAIR(i + 3, j0, hp0[6], hy0[6]);
        HPAIR(i + 3, j1, hp1[6], hy1[6]);

        float S0  = ((hp0[0]+hp0[6])+(hp0[1]+hp0[5])) + ((hp0[2]+hp0[4])+hp0[3]);
        float Sx0 = 3.f*(hp0[6]-hp0[0]) + 2.f*(hp0[5]-hp0[1]) + (hp0[4]-hp0[2]);
        float Sy0 = ((hy0[0]+hy0[6])+(hy0[1]+hy0[5])) + ((hy0[2]+hy0[4])+hy0[3]);
        float S1  = ((hp1[0]+hp1[6])+(hp1[1]+hp1[5])) + ((hp1[2]+hp1[4])+hp1[3]);
        float Sx1 = 3.f*(hp1[6]-hp1[0]) + 2.f*(hp1[5]-hp1[1]) + (hp1[4]-hp1[2]);
        float Sy1 = ((hy1[0]+hy1[6])+(hy1[1]+hy1[5])) + ((hy1[2]+hy1[4])+hy1[3]);

        if (act) {
            size_t ma = (mrow + j0) * 8;
            size_t mbq = (mrow + j1) * 8;
            d0[ma]  = __float2bfloat16(Sx0);
            d1[ma]  = __float2bfloat16(Sy0);
            d2[ma]  = __float2bfloat16(S0);
            d0[mbq] = __float2bfloat16(Sx1);
            d1[mbq] = __float2bfloat16(Sy1);
            d2[mbq] = __float2bfloat16(S1);
        }
        mrow += WW;
#pragma unroll
        for (int q = 0; q < 6; ++q) {
            hp0[q] = hp0[q+1]; hy0[q] = hy0[q+1];
            hp1[q] = hp1[q+1]; hy1[q] = hy1[q+1];
        }
    }
#undef HPAIR
}

// ---------------- kernel 2: GEMM out[m][o] = sum_k dcg[k][m]*abc[k][o] + bias ----------------
// block = 256 thr = 4 waves; wave w handles o in [w*32, w*32+32), pixel tile of 64.
// grid.x = nb * 196   (12544/64 pixel tiles per batch)
__global__ __launch_bounds__(256, 2) void k_gemm(const __hip_bfloat16* __restrict__ dcg,
                                                 const __hip_bfloat16* __restrict__ abct,
                                                 const float* __restrict__ bias,
                                                 float* __restrict__ out,
                                                 int chunk_base, int Mc) {
    int tile = blockIdx.x;
    int bb = tile / 196;
    int mt = tile % 196;
    int m0 = mt * 64;

    int l  = threadIdx.x & 63;
    int wv = threadIdx.x >> 6;
    int o0 = wv * 32;
    int lg = l >> 4;      // k-group within fragment
    int lr = l & 15;      // row/col within fragment

    const ushort* at = (const ushort*)abct;
    const ushort* dg = (const ushort*)dcg;

    // preload all abc A-fragments for this wave's 32 output channels (96 VGPRs)
    bf16x8 afrag[12][2];
#pragma unroll
    for (int kc = 0; kc < 12; ++kc)
#pragma unroll
        for (int fi = 0; fi < 2; ++fi) {
            const ushort* p = at + (size_t)(o0 + fi * 16 + lr) * K3 + kc * 32 + lg * 8;
            afrag[kc][fi] = *(const bf16x8*)p;
        }

    // bias per (fi,r)
    float bv[2][4];
#pragma unroll
    for (int fi = 0; fi < 2; ++fi)
#pragma unroll
        for (int r = 0; r < 4; ++r)
            bv[fi][r] = bias[o0 + fi * 16 + lg * 4 + r];

    f32x4 acc[2][4] = {};
    size_t mbase = (size_t)bb * HW + m0;

#pragma unroll
    for (int kc = 0; kc < 12; ++kc) {
        bf16x8 bfrag[4];
#pragma unroll
        for (int pj = 0; pj < 4; ++pj) {
            const ushort* p = dg + ((size_t)(kc * 4 + lg) * Mc + mbase + pj * 16 + lr) * 8;
            bfrag[pj] = *(const bf16x8*)p;
        }
#pragma unroll
        for (int fi = 0; fi < 2; ++fi)
#pragma unroll
            for (int pj = 0; pj < 4; ++pj)
                acc[fi][pj] = __builtin_amdgcn_mfma_f32_16x16x32_bf16(
                    afrag[kc][fi], bfrag[pj], acc[fi][pj], 0, 0, 0);
    }

    // store: D col = pixel (lr), row = o = o0 + fi*16 + lg*4 + r
    int b = chunk_base + bb;
#pragma unroll
    for (int fi = 0; fi < 2; ++fi) {
#pragma unroll
        for (int r = 0; r < 4; ++r) {
            int o = o0 + fi * 16 + lg * 4 + r;
            float* po = out + ((size_t)b * COUT + o) * HW + m0 + lr;
#pragma unroll
            for (int pj = 0; pj < 4; ++pj)
                po[pj * 16] = acc[fi][pj][r] + bv[fi][r];
        }
    }
}

// ---------------- launcher ----------------
extern "C" void kernel_launch(void* const* d_in, const int* in_sizes, int n_in,
                              void* d_out, int out_size, void* d_ws, size_t ws_size,
                              hipStream_t stream) {
    const float* x    = (const float*)d_in[0];
    const float* abc  = (const float*)d_in[1];
    const float* bias = (const float*)d_in[2];
    float* out = (float*)d_out;

    char* ws = (char*)d_ws;
    __hip_bfloat16* abct = (__hip_bfloat16*)ws;                  // 96 KB
    __hip_bfloat16* dcg  = (__hip_bfloat16*)(ws + 131072);       // 16B-aligned

    const size_t per_batch = (size_t)48 * HW * 16;               // 9,633,792 B
    size_t avail = (ws_size > 131072) ? ws_size - 131072 : 0;
    int nb = (int)(avail / per_batch);
    if (nb > NB_ALL) nb = NB_ALL;
    if (nb < 1) nb = 1;

    k_abct<<<dim3((K3 * COUT + 255) / 256), dim3(256), 0, stream>>>(abc, abct);

    for (int b0 = 0; b0 < NB_ALL; b0 += nb) {
        int nbc = (NB_ALL - b0 < nb) ? (NB_ALL - b0) : nb;
        int Mc = nbc * HW;
        k_boxsum<<<dim3(nbc * 16 * 4), dim3(512), 0, stream>>>(x, dcg, b0, Mc);
        k_gemm<<<dim3(nbc * 196), dim3(256), 0, stream>>>(dcg, abct, bias, out, b0, Mc);
    }
}

// Round 7
// 313.815 us; speedup vs baseline: 1.3858x; 1.2086x over previous
//
#include <hip/hip_runtime.h>
#include <hip/hip_bf16.h>

#define CIN 128
#define COUT 128
#define HH 112
#define WW 112
#define HW (HH*WW)      // 12544
#define K3 384          // 3*CIN
#define NB_ALL 16

typedef float f32x4 __attribute__((ext_vector_type(4)));
typedef short bf16x8 __attribute__((ext_vector_type(8)));
typedef int   i32x4 __attribute__((ext_vector_type(4)));

// ---------------- kernel 0: abc (384x128 f32) -> abc_t (128x384 bf16) ----------------
__global__ __launch_bounds__(256) void k_abct(const float* __restrict__ abc,
                                              __hip_bfloat16* __restrict__ abct) {
    int idx = blockIdx.x * 256 + threadIdx.x;
    if (idx >= K3 * COUT) return;
    int o = idx & 127, k = idx >> 7;
    abct[o * K3 + k] = __float2bfloat16(abc[k * COUT + o]);
}

// ---------------- kernel 1: separable box sums -> dcg k8-packed bf16 ----------------
// dcg layout: [kb=k/8][m][e=k%8], m = bb*HW + i*WW + j
// Stores routed through LDS: 4-row double-buffered groups, cooperative full-line flush.
// block: 512 threads = 8 waves; wave w -> channel c = cg*8+w (e=w)
// grid.x = nbc * 16(cg) * 4(ig row strips of 28)
__global__ __launch_bounds__(512) void k_boxsum(const float* __restrict__ x,
                                                __hip_bfloat16* __restrict__ dcg,
                                                int chunk_base, int Mc) {
    // sbuf[fb 2][part 3][row 4][j 112][e 8] bf16 = 43008 B
    __shared__ __hip_bfloat16 sbuf[2 * 3 * 448 * 8];

    int bidx = blockIdx.x;
    int ig = bidx & 3; bidx >>= 2;
    int cg = bidx & 15; bidx >>= 4;
    int bb = bidx;
    int w    = threadIdx.x >> 6;
    int lane = threadIdx.x & 63;
    int c = cg * 8 + w;

    const float* xc = x + ((size_t)(chunk_base + bb) * CIN + c) * HW;

    int i0 = ig * 28;
    bool act = lane < 56;
    int j0 = lane;        // half 0 output col
    int j1 = 56 + lane;   // half 1 output col

    float hp0[7], hy0[7], hp1[7], hy1[7];

#define HPAIR(r, j, HP, HY) do {                                               \
    int _r = (r);                                                              \
    if ((unsigned)_r >= HH) { HP = 0.f; HY = 0.f; }                            \
    else {                                                                     \
        const float* row = xc + _r * WW;                                       \
        int _j = (j);                                                          \
        float s0 = ((unsigned)(_j-3) < WW) ? row[_j-3] : 0.f;                  \
        float s1 = ((unsigned)(_j-2) < WW) ? row[_j-2] : 0.f;                  \
        float s2 = ((unsigned)(_j-1) < WW) ? row[_j-1] : 0.f;                  \
        float s3 = ((unsigned)(_j  ) < WW) ? row[_j  ] : 0.f;                  \
        float s4 = ((unsigned)(_j+1) < WW) ? row[_j+1] : 0.f;                  \
        float s5 = ((unsigned)(_j+2) < WW) ? row[_j+2] : 0.f;                  \
        float s6 = ((unsigned)(_j+3) < WW) ? row[_j+3] : 0.f;                  \
        HP = ((s0+s6)+(s1+s5)) + ((s2+s4)+s3);                                 \
        HY = 3.f*(s6-s0) + 2.f*(s5-s1) + (s4-s2);                              \
    }                                                                          \
} while (0)

#pragma unroll
    for (int q = 0; q < 6; ++q) {
        HPAIR(i0 - 3 + q, j0, hp0[q], hy0[q]);
        HPAIR(i0 - 3 + q, j1, hp1[q], hy1[q]);
    }

    int tid = threadIdx.x;

    for (int f = 0; f < 7; ++f) {             // 7 groups of 4 rows = 28 rows
        int fb = f & 1;
#pragma unroll
        for (int rr = 0; rr < 4; ++rr) {
            int i = i0 + f * 4 + rr;
            HPAIR(i + 3, j0, hp0[6], hy0[6]);
            HPAIR(i + 3, j1, hp1[6], hy1[6]);

            float S0  = ((hp0[0]+hp0[6])+(hp0[1]+hp0[5])) + ((hp0[2]+hp0[4])+hp0[3]);
            float Sx0 = 3.f*(hp0[6]-hp0[0]) + 2.f*(hp0[5]-hp0[1]) + (hp0[4]-hp0[2]);
            float Sy0 = ((hy0[0]+hy0[6])+(hy0[1]+hy0[5])) + ((hy0[2]+hy0[4])+hy0[3]);
            float S1  = ((hp1[0]+hp1[6])+(hp1[1]+hp1[5])) + ((hp1[2]+hp1[4])+hp1[3]);
            float Sx1 = 3.f*(hp1[6]-hp1[0]) + 2.f*(hp1[5]-hp1[1]) + (hp1[4]-hp1[2]);
            float Sy1 = ((hy1[0]+hy1[6])+(hy1[1]+hy1[5])) + ((hy1[2]+hy1[4])+hy1[3]);

            if (act) {
                int base = (fb * 3 * 448 + rr * 112) * 8 + w;   // part stride = 448*8
                sbuf[base + 0*3584 + j0*8] = __float2bfloat16(Sx0);
                sbuf[base + 1*3584 + j0*8] = __float2bfloat16(Sy0);
                sbuf[base + 2*3584 + j0*8] = __float2bfloat16(S0);
                sbuf[base + 0*3584 + j1*8] = __float2bfloat16(Sx1);
                sbuf[base + 1*3584 + j1*8] = __float2bfloat16(Sy1);
                sbuf[base + 2*3584 + j1*8] = __float2bfloat16(S1);
            }
#pragma unroll
            for (int q = 0; q < 6; ++q) {
                hp0[q] = hp0[q+1]; hy0[q] = hy0[q+1];
                hp1[q] = hp1[q+1]; hy1[q] = hy1[q+1];
            }
        }
        __syncthreads();
        // flush fb: 3 parts x 448 pixels = 1344 chunks of 16B, fully coalesced
        size_t mrow0 = (size_t)bb * HW + (size_t)(i0 + f * 4) * WW;
#pragma unroll
        for (int rep = 0; rep < 3; ++rep) {
            int idx = tid + rep * 512;
            if (idx < 1344) {
                int p = idx / 448;
                int pix = idx - p * 448;
                bf16x8 v = *(const bf16x8*)&sbuf[((fb * 3 + p) * 448 + pix) * 8];
                __hip_bfloat16* dst = dcg + ((size_t)(p * 16 + cg) * Mc + mrow0 + pix) * 8;
                *(bf16x8*)dst = v;
            }
        }
    }
#undef HPAIR
}

// ---------------- kernel 2: LDS double-buffered GEMM ----------------
// out[m][o] = sum_k dcg[k][m]*abct[o][k] + bias[o]
// tile: M=128 pixels, N=128 o (all), BK=64; 4 waves in 2(m) x 2(o)
// LDS 64KB: A dbuf 2x16KB (dcg tile, [kb 8][m 128][e8], m XOR kb&7 swizzled)
//           B dbuf 2x16KB (abct tile, [o 128][kslot 8], kslot XOR o&7 swizzled)
// grid.x = nbc * 98
__global__ __launch_bounds__(256, 2) void k_gemm(const __hip_bfloat16* __restrict__ dcg,
                                                 const __hip_bfloat16* __restrict__ abct,
                                                 const float* __restrict__ bias,
                                                 float* __restrict__ out,
                                                 int chunk_base, int Mc) {
    __shared__ ushort lds[32768];   // 64 KB
    const int AB0 = 0, AB1 = 8192, BB0 = 16384, BB1 = 24576;

    int tile = blockIdx.x;
    int bb = tile / 98, mt = tile % 98;
    int m0 = mt * 128;
    int tid = threadIdx.x, l = tid & 63, wv = tid >> 6;
    int mq = wv & 1, oq = wv >> 1;
    int lr = l & 15, lg = l >> 4;

    const ushort* dg = (const ushort*)dcg;
    const ushort* at = (const ushort*)abct;
    size_t mbase = (size_t)bb * HW + m0;

    // ---- staging address precompute (per-lane) ----
    bool isA = (wv < 2);
    int aw = wv & 1;
    size_t gsrc[8];
    int    lw[8];
    if (isA) {
#pragma unroll
        for (int q = 0; q < 4; ++q) {
            int kbw = aw * 4 + q;
#pragma unroll
            for (int h = 0; h < 2; ++h) {
                int idx = q * 2 + h;
                int mlds = h * 64 + l;
                gsrc[idx] = ((size_t)kbw * Mc + mbase + mlds) * 8;
                lw[idx]   = kbw * 1024 + (h * 64 + (l ^ (kbw & 7))) * 8;
            }
        }
    } else {
#pragma unroll
        for (int q = 0; q < 8; ++q) {
            int o = aw * 64 + q * 8 + (l >> 3);
            int s = l & 7;
            gsrc[q] = (size_t)o * K3 + s * 8;
            lw[q]   = o * 64 + ((s ^ (o & 7)) * 8);
        }
    }
    size_t astep = (size_t)8 * Mc * 8;   // per K-step advance for A (ushort units)

    // ---- fragment LDS offsets (within buffer, ushort units) ----
    int aoff[4][2], boff[4][2];
#pragma unroll
    for (int fi = 0; fi < 4; ++fi)
#pragma unroll
        for (int kc = 0; kc < 2; ++kc) {
            int ol = oq * 64 + fi * 16 + lr;
            aoff[fi][kc] = ol * 64 + (((kc * 4 + lg) ^ (lr & 7)) * 8);
        }
#pragma unroll
    for (int pj = 0; pj < 4; ++pj)
#pragma unroll
        for (int kc = 0; kc < 2; ++kc) {
            int kb = kc * 4 + lg;
            boff[pj][kc] = kb * 1024 + ((mq * 64 + pj * 16) + (lr ^ (kb & 7))) * 8;
        }

    // ---- prologue: stage step 0 into buffer 0 ----
    {
        i32x4 rs[8];
#pragma unroll
        for (int q = 0; q < 8; ++q)
            rs[q] = isA ? *(const i32x4*)(dg + gsrc[q]) : *(const i32x4*)(at + gsrc[q]);
        int base = isA ? AB0 : BB0;
#pragma unroll
        for (int q = 0; q < 8; ++q)
            *(i32x4*)&lds[base + lw[q]] = rs[q];
    }
    __syncthreads();

    f32x4 acc[4][4] = {};

#pragma unroll
    for (int st = 0; st < 6; ++st) {
        int cb = st & 1;
        int Ac = cb ? AB1 : AB0, Bc = cb ? BB1 : BB0;
        int An = cb ? AB0 : AB1, Bn = cb ? BB0 : BB1;

        // issue next-step loads early
        i32x4 rs[8];
        if (st < 5) {
#pragma unroll
            for (int q = 0; q < 8; ++q) {
                if (isA) rs[q] = *(const i32x4*)(dg + gsrc[q] + (size_t)(st + 1) * astep);
                else     rs[q] = *(const i32x4*)(at + gsrc[q] + (size_t)(st + 1) * 64);
            }
        }

        // compute current step
#pragma unroll
        for (int kc = 0; kc < 2; ++kc) {
            bf16x8 af[4], bf[4];
#pragma unroll
            for (int fi = 0; fi < 4; ++fi)
                af[fi] = *(const bf16x8*)&lds[Bc + aoff[fi][kc]];
#pragma unroll
            for (int pj = 0; pj < 4; ++pj)
                bf[pj] = *(const bf16x8*)&lds[Ac + boff[pj][kc]];
#pragma unroll
            for (int fi = 0; fi < 4; ++fi)
#pragma unroll
                for (int pj = 0; pj < 4; ++pj)
                    acc[fi][pj] = __builtin_amdgcn_mfma_f32_16x16x32_bf16(
                        af[fi], bf[pj], acc[fi][pj], 0, 0, 0);
        }

        // write next-step tile
        if (st < 5) {
            int base = isA ? An : Bn;
#pragma unroll
            for (int q = 0; q < 8; ++q)
                *(i32x4*)&lds[base + lw[q]] = rs[q];
        }
        __syncthreads();
    }

    // ---- epilogue: D col=pixel(lr), row = o = oq*64 + fi*16 + lg*4 + r ----
    int b = chunk_base + bb;
#pragma unroll
    for (int fi = 0; fi < 4; ++fi) {
#pragma unroll
        for (int r = 0; r < 4; ++r) {
            int o = oq * 64 + fi * 16 + lg * 4 + r;
            float bvv = bias[o];
            float* po = out + ((size_t)b * COUT + o) * HW + m0 + mq * 64 + lr;
#pragma unroll
            for (int pj = 0; pj < 4; ++pj)
                po[pj * 16] = acc[fi][pj][r] + bvv;
        }
    }
}

// ---------------- launcher ----------------
extern "C" void kernel_launch(void* const* d_in, const int* in_sizes, int n_in,
                              void* d_out, int out_size, void* d_ws, size_t ws_size,
                              hipStream_t stream) {
    const float* x    = (const float*)d_in[0];
    const float* abc  = (const float*)d_in[1];
    const float* bias = (const float*)d_in[2];
    float* out = (float*)d_out;

    char* ws = (char*)d_ws;
    __hip_bfloat16* abct = (__hip_bfloat16*)ws;                  // 96 KB
    __hip_bfloat16* dcg  = (__hip_bfloat16*)(ws + 131072);

    const size_t per_batch = (size_t)48 * HW * 16;               // 9,633,792 B
    size_t avail = (ws_size > 131072) ? ws_size - 131072 : 0;
    int nb = (int)(avail / per_batch);
    if (nb > NB_ALL) nb = NB_ALL;
    if (nb < 1) nb = 1;

    k_abct<<<dim3((K3 * COUT + 255) / 256), dim3(256), 0, stream>>>(abc, abct);

    for (int b0 = 0; b0 < NB_ALL; b0 += nb) {
        int nbc = (NB_ALL - b0 < nb) ? (NB_ALL - b0) : nb;
        int Mc = nbc * HW;
        k_boxsum<<<dim3(nbc * 16 * 4), dim3(512), 0, stream>>>(x, dcg, b0, Mc);
        k_gemm<<<dim3(nbc * 98), dim3(256), 0, stream>>>(dcg, abct, bias, out, b0, Mc);
    }
}

// Round 8
// 287.997 us; speedup vs baseline: 1.5100x; 1.0896x over previous
//
#include <hip/hip_runtime.h>
#include <hip/hip_bf16.h>

#define CIN 128
#define COUT 128
#define HH 112
#define WW 112
#define HW (HH*WW)      // 12544
#define K3 384          // 3*CIN
#define NB_ALL 16

typedef float f32x4 __attribute__((ext_vector_type(4)));
typedef short bf16x8 __attribute__((ext_vector_type(8)));
typedef int   i32x4 __attribute__((ext_vector_type(4)));

// ---------------- kernel 0: abc (384x128 f32) -> abc_t (128x384 bf16) ----------------
__global__ __launch_bounds__(256) void k_abct(const float* __restrict__ abc,
                                              __hip_bfloat16* __restrict__ abct) {
    int idx = blockIdx.x * 256 + threadIdx.x;
    if (idx >= K3 * COUT) return;
    int o = idx & 127, k = idx >> 7;
    abct[o * K3 + k] = __float2bfloat16(abc[k * COUT + o]);
}

// ---------------- kernel 1: separable box sums -> dcg k8-packed bf16 ----------------
// dcg layout: [kb=k/8][m][e=k%8], m = bb*HW + i*WW + j
// 2-row LDS flush groups (21.5 KB), software-pipelined tap loads.
// block: 512 threads = 8 waves; wave w -> channel c = cg*8+w (e=w)
// grid.x = nbc * 16(cg) * 4(ig row strips of 28)
__global__ __launch_bounds__(512) void k_boxsum(const float* __restrict__ x,
                                                __hip_bfloat16* __restrict__ dcg,
                                                int chunk_base, int Mc) {
    // sbuf[fb 2][part 3][rr 2][j 112][e 8] bf16 = 21504 B
    __shared__ __hip_bfloat16 sbuf[2 * 3 * 2 * 112 * 8];

    int bidx = blockIdx.x;
    int ig = bidx & 3; bidx >>= 2;
    int cg = bidx & 15; bidx >>= 4;
    int bb = bidx;
    int w    = threadIdx.x >> 6;
    int lane = threadIdx.x & 63;
    int c = cg * 8 + w;

    const float* xc = x + ((size_t)(chunk_base + bb) * CIN + c) * HW;

    int i0 = ig * 28;
    bool act = lane < 56;
    int j0 = lane;        // half 0 output col (taps j0-3..j0+3, high side always in-bounds)
    int j1 = 56 + lane;   // half 1 output col (taps j1-3..j1+3, low side in-bounds for act lanes)

    float hp0[7], hy0[7], hp1[7], hy1[7];

    // prologue horizontal pair (fully guarded, used 6x at start only)
#define HPAIR(r, j, HP, HY) do {                                               \
    int _r = (r);                                                              \
    if ((unsigned)_r >= HH) { HP = 0.f; HY = 0.f; }                            \
    else {                                                                     \
        const float* row = xc + _r * WW;                                       \
        int _j = (j);                                                          \
        float s0 = ((unsigned)(_j-3) < WW) ? row[_j-3] : 0.f;                  \
        float s1 = ((unsigned)(_j-2) < WW) ? row[_j-2] : 0.f;                  \
        float s2 = ((unsigned)(_j-1) < WW) ? row[_j-1] : 0.f;                  \
        float s3 = ((unsigned)(_j  ) < WW) ? row[_j  ] : 0.f;                  \
        float s4 = ((unsigned)(_j+1) < WW) ? row[_j+1] : 0.f;                  \
        float s5 = ((unsigned)(_j+2) < WW) ? row[_j+2] : 0.f;                  \
        float s6 = ((unsigned)(_j+3) < WW) ? row[_j+3] : 0.f;                  \
        HP = ((s0+s6)+(s1+s5)) + ((s2+s4)+s3);                                 \
        HY = 3.f*(s6-s0) + 2.f*(s5-s1) + (s4-s2);                              \
    }                                                                          \
} while (0)

#pragma unroll
    for (int q = 0; q < 6; ++q) {
        HPAIR(i0 - 3 + q, j0, hp0[q], hy0[q]);
        HPAIR(i0 - 3 + q, j1, hp1[q], hy1[q]);
    }

    // pipelined tap loads for the NEXT input row (consumed one iteration later)
    float ntA[7], ntB[7];
#define LOADT(r) do {                                                          \
    int _r = (r);                                                              \
    if ((unsigned)_r >= HH) {                                                  \
        ntA[0]=ntA[1]=ntA[2]=ntA[3]=ntA[4]=ntA[5]=ntA[6]=0.f;                  \
        ntB[0]=ntB[1]=ntB[2]=ntB[3]=ntB[4]=ntB[5]=ntB[6]=0.f;                  \
    } else {                                                                   \
        const float* row = xc + _r * WW;                                       \
        ntA[0] = (j0-3 >= 0) ? row[j0-3] : 0.f;                                \
        ntA[1] = (j0-2 >= 0) ? row[j0-2] : 0.f;                                \
        ntA[2] = (j0-1 >= 0) ? row[j0-1] : 0.f;                                \
        ntA[3] = row[j0];                                                      \
        ntA[4] = row[j0+1];                                                    \
        ntA[5] = row[j0+2];                                                    \
        ntA[6] = row[j0+3];                                                    \
        ntB[0] = ((unsigned)(j1-3) < WW) ? row[j1-3] : 0.f;                    \
        ntB[1] = ((unsigned)(j1-2) < WW) ? row[j1-2] : 0.f;                    \
        ntB[2] = ((unsigned)(j1-1) < WW) ? row[j1-1] : 0.f;                    \
        ntB[3] = ((unsigned)(j1  ) < WW) ? row[j1  ] : 0.f;                    \
        ntB[4] = ((unsigned)(j1+1) < WW) ? row[j1+1] : 0.f;                    \
        ntB[5] = ((unsigned)(j1+2) < WW) ? row[j1+2] : 0.f;                    \
        ntB[6] = ((unsigned)(j1+3) < WW) ? row[j1+3] : 0.f;                    \
    }                                                                          \
} while (0)

    LOADT(i0 + 3);

    int tid = threadIdx.x;

    for (int f = 0; f < 14; ++f) {            // 14 groups of 2 rows = 28 rows
        int fb = f & 1;
#pragma unroll
        for (int rr = 0; rr < 2; ++rr) {
            int i = i0 + f * 2 + rr;
            // consume prefetched taps -> new horizontal pair
            hp0[6] = ((ntA[0]+ntA[6])+(ntA[1]+ntA[5])) + ((ntA[2]+ntA[4])+ntA[3]);
            hy0[6] = 3.f*(ntA[6]-ntA[0]) + 2.f*(ntA[5]-ntA[1]) + (ntA[4]-ntA[2]);
            hp1[6] = ((ntB[0]+ntB[6])+(ntB[1]+ntB[5])) + ((ntB[2]+ntB[4])+ntB[3]);
            hy1[6] = 3.f*(ntB[6]-ntB[0]) + 2.f*(ntB[5]-ntB[1]) + (ntB[4]-ntB[2]);
            // issue next row's loads early (consumed next iteration)
            LOADT(i + 4);

            float S0  = ((hp0[0]+hp0[6])+(hp0[1]+hp0[5])) + ((hp0[2]+hp0[4])+hp0[3]);
            float Sx0 = 3.f*(hp0[6]-hp0[0]) + 2.f*(hp0[5]-hp0[1]) + (hp0[4]-hp0[2]);
            float Sy0 = ((hy0[0]+hy0[6])+(hy0[1]+hy0[5])) + ((hy0[2]+hy0[4])+hy0[3]);
            float S1  = ((hp1[0]+hp1[6])+(hp1[1]+hp1[5])) + ((hp1[2]+hp1[4])+hp1[3]);
            float Sx1 = 3.f*(hp1[6]-hp1[0]) + 2.f*(hp1[5]-hp1[1]) + (hp1[4]-hp1[2]);
            float Sy1 = ((hy1[0]+hy1[6])+(hy1[1]+hy1[5])) + ((hy1[2]+hy1[4])+hy1[3]);

            if (act) {
                int b0 = (fb * 6 + rr) * 896 + w;       // part stride = 2*896
                sbuf[b0 + 0 * 1792 + j0 * 8] = __float2bfloat16(Sx0);
                sbuf[b0 + 1 * 1792 + j0 * 8] = __float2bfloat16(Sy0);
                sbuf[b0 + 2 * 1792 + j0 * 8] = __float2bfloat16(S0);
                sbuf[b0 + 0 * 1792 + j1 * 8] = __float2bfloat16(Sx1);
                sbuf[b0 + 1 * 1792 + j1 * 8] = __float2bfloat16(Sy1);
                sbuf[b0 + 2 * 1792 + j1 * 8] = __float2bfloat16(S1);
            }
#pragma unroll
            for (int q = 0; q < 6; ++q) {
                hp0[q] = hp0[q+1]; hy0[q] = hy0[q+1];
                hp1[q] = hp1[q+1]; hy1[q] = hy1[q+1];
            }
        }
        __syncthreads();
        // flush: 3 parts x 2 rows x 112 pixels = 672 chunks of 16B
        size_t mrow0 = (size_t)bb * HW + (size_t)(i0 + f * 2) * WW;
#pragma unroll
        for (int rep = 0; rep < 2; ++rep) {
            int idx = tid + rep * 512;
            if (idx < 672) {
                int p = idx / 224;
                int rem = idx - p * 224;
                int rr2 = rem / 112;
                int j = rem - rr2 * 112;
                bf16x8 v = *(const bf16x8*)&sbuf[(fb * 6 + p * 2 + rr2) * 896 + j * 8];
                __hip_bfloat16* dst = dcg + ((size_t)(p * 16 + cg) * Mc + mrow0 + rr2 * WW + j) * 8;
                *(bf16x8*)dst = v;
            }
        }
    }
#undef HPAIR
#undef LOADT
}

// ---------------- kernel 2: dbuf GEMM, BK=32, global_load_lds A-staging ----------------
// out[m][o] = sum_k dcg[k][m]*abct[o][k] + bias[o]
// tile M=128 pix, N=128 o, BK=32; 4 waves 2(m)x2(o); 12 K-steps
// LDS 32KB: A dbuf 2x8KB ([kb 4][pix 128][e 8], linear), B dbuf 2x8KB ([o 128][slot^key 4][8])
// grid.x = nbc * 98
__global__ __launch_bounds__(256, 3) void k_gemm(const __hip_bfloat16* __restrict__ dcg,
                                                 const __hip_bfloat16* __restrict__ abct,
                                                 const float* __restrict__ bias,
                                                 float* __restrict__ out,
                                                 int chunk_base, int Mc) {
    __shared__ ushort lds[16384];   // 32 KB
    const int A0 = 0, A1 = 4096, B0 = 8192, B1 = 12288;

    int tile = blockIdx.x;
    int bb = tile / 98, mt = tile % 98;
    int m0 = mt * 128;
    int tid = threadIdx.x, l = tid & 63, wv = tid >> 6;
    int mq = wv & 1, oq = wv >> 1;
    int lr = l & 15, lg = l >> 4;

    const ushort* dg = (const ushort*)dcg;
    const ushort* at = (const ushort*)abct;
    size_t mbase = (size_t)bb * HW + m0;

    // B staging (abct): each lane covers 32B of one o-row
    int ow = wv * 32 + (l >> 1);
    int half = l & 1;
    int key = (ow >> 1) & 3;
    int bdst0 = ow * 32 + (((half * 2 + 0) ^ key) * 8);
    int bdst1 = ow * 32 + (((half * 2 + 1) ^ key) * 8);
    size_t bsrc0 = (size_t)ow * K3 + (half * 2 + 0) * 8;
    size_t bsrc1 = (size_t)ow * K3 + (half * 2 + 1) * 8;

    // A staging (dcg) via global_load_lds: wave wv -> kb=wv, 2 chunks of 1KB
    size_t asrc0 = ((size_t)wv * Mc + mbase + 0 * 64 + l) * 8;
    size_t asrc1 = ((size_t)wv * Mc + mbase + 1 * 64 + l) * 8;
    size_t astep = (size_t)4 * Mc * 8;
    int adst0 = wv * 1024;
    int adst1 = wv * 1024 + 512;

#define GLOADLDS(gofs, ldsofs) __builtin_amdgcn_global_load_lds( \
        (const __attribute__((address_space(1))) void*)(dg + (gofs)), \
        (__attribute__((address_space(3))) void*)&lds[(ldsofs)], 16, 0, 0)

    // fragment read offsets (ushort units, within buffer)
    int aoffu[4], boffu[4];
#pragma unroll
    for (int fi = 0; fi < 4; ++fi) {
        int o = oq * 64 + fi * 16 + lr;
        aoffu[fi] = o * 32 + ((lg ^ ((o >> 1) & 3)) * 8);
    }
#pragma unroll
    for (int pj = 0; pj < 4; ++pj)
        boffu[pj] = lg * 1024 + (mq * 64 + pj * 16 + lr) * 8;

    // prologue: stage step 0
    GLOADLDS(asrc0, A0 + adst0);
    GLOADLDS(asrc1, A0 + adst1);
    {
        i32x4 rb0 = *(const i32x4*)(at + bsrc0);
        i32x4 rb1 = *(const i32x4*)(at + bsrc1);
        *(i32x4*)&lds[B0 + bdst0] = rb0;
        *(i32x4*)&lds[B0 + bdst1] = rb1;
    }
    __syncthreads();

    f32x4 acc[4][4] = {};

#pragma unroll
    for (int st = 0; st < 12; ++st) {
        int cb = st & 1;
        int Ac = cb ? A1 : A0, Bc = cb ? B1 : B0;
        int An = cb ? A0 : A1, Bn = cb ? B0 : B1;

        i32x4 nb0, nb1;
        if (st < 11) {
            GLOADLDS(asrc0 + (size_t)(st + 1) * astep, An + adst0);
            GLOADLDS(asrc1 + (size_t)(st + 1) * astep, An + adst1);
            nb0 = *(const i32x4*)(at + bsrc0 + (st + 1) * 32);
            nb1 = *(const i32x4*)(at + bsrc1 + (st + 1) * 32);
        }

        bf16x8 af[4], bfr[4];
#pragma unroll
        for (int fi = 0; fi < 4; ++fi)
            af[fi] = *(const bf16x8*)&lds[Bc + aoffu[fi]];
#pragma unroll
        for (int pj = 0; pj < 4; ++pj)
            bfr[pj] = *(const bf16x8*)&lds[Ac + boffu[pj]];
#pragma unroll
        for (int fi = 0; fi < 4; ++fi)
#pragma unroll
            for (int pj = 0; pj < 4; ++pj)
                acc[fi][pj] = __builtin_amdgcn_mfma_f32_16x16x32_bf16(
                    af[fi], bfr[pj], acc[fi][pj], 0, 0, 0);

        if (st < 11) {
            *(i32x4*)&lds[Bn + bdst0] = nb0;
            *(i32x4*)&lds[Bn + bdst1] = nb1;
        }
        __syncthreads();
    }
#undef GLOADLDS

    // epilogue: D col=pixel(lr), row o = oq*64 + fi*16 + lg*4 + r
    int b = chunk_base + bb;
#pragma unroll
    for (int fi = 0; fi < 4; ++fi) {
#pragma unroll
        for (int r = 0; r < 4; ++r) {
            int o = oq * 64 + fi * 16 + lg * 4 + r;
            float bvv = bias[o];
            float* po = out + ((size_t)b * COUT + o) * HW + m0 + mq * 64 + lr;
#pragma unroll
            for (int pj = 0; pj < 4; ++pj)
                po[pj * 16] = acc[fi][pj][r] + bvv;
        }
    }
}

// ---------------- launcher ----------------
extern "C" void kernel_launch(void* const* d_in, const int* in_sizes, int n_in,
                              void* d_out, int out_size, void* d_ws, size_t ws_size,
                              hipStream_t stream) {
    const float* x    = (const float*)d_in[0];
    const float* abc  = (const float*)d_in[1];
    const float* bias = (const float*)d_in[2];
    float* out = (float*)d_out;

    char* ws = (char*)d_ws;
    __hip_bfloat16* abct = (__hip_bfloat16*)ws;                  // 96 KB
    __hip_bfloat16* dcg  = (__hip_bfloat16*)(ws + 131072);

    const size_t per_batch = (size_t)48 * HW * 16;               // 9,633,792 B
    size_t avail = (ws_size > 131072) ? ws_size - 131072 : 0;
    int nb = (int)(avail / per_batch);
    if (nb > NB_ALL) nb = NB_ALL;
    if (nb < 1) nb = 1;

    k_abct<<<dim3((K3 * COUT + 255) / 256), dim3(256), 0, stream>>>(abc, abct);

    for (int b0 = 0; b0 < NB_ALL; b0 += nb) {
        int nbc = (NB_ALL - b0 < nb) ? (NB_ALL - b0) : nb;
        int Mc = nbc * HW;
        k_boxsum<<<dim3(nbc * 16 * 4), dim3(512), 0, stream>>>(x, dcg, b0, Mc);
        k_gemm<<<dim3(nbc * 98), dim3(256), 0, stream>>>(dcg, abct, bias, out, b0, Mc);
    }
}